// Round 4
// baseline (209.904 us; speedup 1.0000x reference)
//
#include <hip/hip_runtime.h>

// CIN cross-network, fused MFMA implementation (f16 inputs, fp32 accum).
// Round 4: conflict-free x0 scalar layout (stride-33 f16 rows), contiguous
// per-K-block B fragments (immediate offsets), coalesced LDS-transpose prep.
//
// y[b,n,d] = relu( sum_{m,h} x0[b,m,d] * xk[b,h,d] * W[m,h,n] )
// out[b, 64*l + n] = sum_d y  (per layer l)
//
// Per-wave: 4 private batches; all LDS regions wave-private => NO barriers
// in cin_main.

typedef _Float16 half8 __attribute__((ext_vector_type(8)));
typedef _Float16 half2v __attribute__((ext_vector_type(2)));
typedef float f32x4 __attribute__((ext_vector_type(4)));

#define OUT_STRIDE 192
#define X0R 33            // x0 row stride (f16): 66B -> column reads hit 16
                          // distinct banks (floor((33r+m)/2)%32 injective in r)
#define X0B (16 * X0R)    // 528 f16 per batch
#define XKR 72            // xk row stride: 64 + 8 pad (16B-aligned, 2-way max)
#define XKB 1152          // xk batch stride

// ---------------------------------------------------------------------------
// Weight repack. Key identity: (m*H+h) == k, so W_flat is already [k][n] and
// the source for one 32-k block (kb) is a CONTIGUOUS 8KB tile. Stage it in
// LDS (row pad 65 breaks the j-sweep bank aliasing), emit in fragment order:
//   dst[((kb*4 + t)*64 + lane)*8 + j] = W[k*64 + n],
//   k = kb*32 + (lane>>4)*8 + j,  n = t*16 + (lane&15)
// Both global read and global write fully coalesced (half8 stores).
__global__ void prep_w_all(const float* __restrict__ W0,
                           const float* __restrict__ W1,
                           const float* __restrict__ W2,
                           _Float16* __restrict__ dst) {
  __shared__ float tile[32 * 65];
  const int tid = threadIdx.x;
  const int blk = blockIdx.x;
  const float* src;
  _Float16* d;
  int kb;
  if (blk < 32)      { src = W0 + (size_t)blk * 2048;        d = dst;          kb = blk; }
  else if (blk < 96) { src = W1 + (size_t)(blk - 32) * 2048; d = dst + 65536;  kb = blk - 32; }
  else               { src = W2 + (size_t)(blk - 96) * 2048; d = dst + 196608; kb = blk - 96; }
#pragma unroll
  for (int i = tid; i < 2048; i += 256)
    tile[(i >> 6) * 65 + (i & 63)] = src[i];
  __syncthreads();
  const int lane = tid & 63, t = tid >> 6;
  const int qq = lane >> 4, n = t * 16 + (lane & 15);
  half8 v;
#pragma unroll
  for (int j = 0; j < 8; ++j)
    v[j] = (_Float16)tile[(qq * 8 + j) * 65 + n];
  *(half8*)(d + (size_t)kb * 2048 + tid * 8) = v;
}

// ---------------------------------------------------------------------------
// One layer for one wave's 4 private batches.
// NHI: 32-wide h-blocks (1 for H=32, 2 for H=64). av[b][hi] in registers.
// x0row0 = x0 LDS base + r*X0R (lane-resolved); scalar reads are conflict-free.
template<int NHI, bool LAST>
__device__ __forceinline__ void run_layer(
    const _Float16* __restrict__ Wp, const half8 (&av)[4][NHI],
    const _Float16* x0row0, _Float16* xkw, float* __restrict__ out,
    long gb0, int loff, int lane, int r, int q)
{
  f32x4 acc[4][4];
#pragma unroll
  for (int b = 0; b < 4; ++b)
#pragma unroll
    for (int t = 0; t < 4; ++t) acc[b][t] = (f32x4){0.f, 0.f, 0.f, 0.f};

#pragma unroll 2
  for (int m = 0; m < 32; ++m) {
    // x0 scalar per batch for this m (splat -> v_pk_mul_f16 operand).
    half2v xs2[4];
#pragma unroll
    for (int b = 0; b < 4; ++b) {
      _Float16 x = x0row0[b * X0B + m];
      xs2[b] = (half2v){x, x};
    }
#pragma unroll
    for (int hi = 0; hi < NHI; ++hi) {
      const int kb = m * NHI + hi;
      const _Float16* pkb = Wp + (size_t)kb * 2048 + lane * 8;
      half8 Bf[4];
#pragma unroll
      for (int t = 0; t < 4; ++t)               // byte offsets 0/1024/2048/3072
        Bf[t] = *(const half8*)(pkb + t * 512); // -> immediate-offset loads
#pragma unroll
      for (int b = 0; b < 4; ++b) {
        half8 af;
        half2v* ap = (half2v*)&af;
        const half2v* vp = (const half2v*)&av[b][hi];
#pragma unroll
        for (int j2 = 0; j2 < 4; ++j2) ap[j2] = vp[j2] * xs2[b];
#pragma unroll
        for (int t = 0; t < 4; ++t)
          acc[b][t] = __builtin_amdgcn_mfma_f32_16x16x32_f16(
              af, Bf[t], acc[b][t], 0, 0, 0);
      }
    }
  }

  // Epilogue (round-1 verified). C/D layout: col n = r, row d = q*4 + reg.
#pragma unroll
  for (int b = 0; b < 4; ++b) {
#pragma unroll
    for (int t = 0; t < 4; ++t) {
      float s = 0.f;
#pragma unroll
      for (int rr = 0; rr < 4; ++rr) {
        float v = acc[b][t][rr];
        v = v > 0.f ? v : 0.f;
        s += v;
        if (!LAST)
          xkw[b * XKB + (q * 4 + rr) * XKR + t * 16 + r] = (_Float16)v;
      }
      s += __shfl_xor(s, 16);
      s += __shfl_xor(s, 32);
      if (q == 0)
        out[(gb0 + b) * OUT_STRIDE + loff + t * 16 + r] = s;
    }
  }
}

__global__ __launch_bounds__(256, 3) void cin_main(
    const float* __restrict__ emb, const _Float16* __restrict__ Wall,
    float* __restrict__ out)
{
  // x0: 16 batches * 528 f16 (16 d rows of stride 33) = 16896 B
  // xk: 16 batches * 1152 f16 (16 d rows of stride 72) = 36864 B
  // total 53760 B -> 3 blocks/CU (161280 <= 163840).
  __shared__ __align__(16) _Float16 lds[16 * X0B + 16 * XKB];
  const int lane = threadIdx.x & 63;
  const int wv = threadIdx.x >> 6;
  const int r = lane & 15, q = lane >> 4;
  const long gb0 = (long)blockIdx.x * 16 + wv * 4;

  _Float16* x0w = &lds[wv * 4 * X0B];
  _Float16* xkw = &lds[16 * X0B + wv * 4 * XKB];

  // Stage this wave's 4 batches: read (m,d) fp32, write transposed (d,m) f16.
#pragma unroll
  for (int bb = 0; bb < 4; ++bb) {
    const float* src = emb + (gb0 + bb) * 512;
    _Float16* dstb = x0w + bb * X0B;
#pragma unroll
    for (int i = 0; i < 2; ++i) {
      int f = i * 256 + lane * 4;         // flat = m*16 + d, d aligned to 4
      float4 v = *(const float4*)(src + f);
      int m = f >> 4, d = f & 15;
      dstb[(d + 0) * X0R + m] = (_Float16)v.x;
      dstb[(d + 1) * X0R + m] = (_Float16)v.y;
      dstb[(d + 2) * X0R + m] = (_Float16)v.z;
      dstb[(d + 3) * X0R + m] = (_Float16)v.w;
    }
  }
  // All LDS regions are wave-private: program order + waitcnt suffice.

  const _Float16* x0row0 = x0w + r * X0R;

  // Layer 1: A-vectors av1[b][j] = x0[m=q*8+j, d=r] (8 scalar reads, one-time;
  // stride-33 rows are only 2B-aligned so no vector load here).
  half8 av1[4][1];
#pragma unroll
  for (int b = 0; b < 4; ++b)
#pragma unroll
    for (int j = 0; j < 8; ++j)
      av1[b][0][j] = x0row0[b * X0B + q * 8 + j];
  run_layer<1, false>(Wall, av1, x0row0, xkw, out, gb0, 0, lane, r, q);

  // Layer 2: A-vectors from xk (h = hi*32 + q*8 + j), 16B-aligned b128 loads.
  half8 av2[4][2];
#pragma unroll
  for (int b = 0; b < 4; ++b)
#pragma unroll
    for (int hi = 0; hi < 2; ++hi)
      av2[b][hi] = *(const half8*)(xkw + b * XKB + r * XKR + hi * 32 + q * 8);
  run_layer<2, false>(Wall + 65536, av2, x0row0, xkw, out, gb0, 64, lane, r, q);

  // Layer 3: reload A-vectors (layer 2 rewrote xk).
#pragma unroll
  for (int b = 0; b < 4; ++b)
#pragma unroll
    for (int hi = 0; hi < 2; ++hi)
      av2[b][hi] = *(const half8*)(xkw + b * XKB + r * XKR + hi * 32 + q * 8);
  run_layer<2, true>(Wall + 196608, av2, x0row0, xkw, out, gb0, 128, lane, r, q);
}

extern "C" void kernel_launch(void* const* d_in, const int* in_sizes, int n_in,
                              void* d_out, int out_size, void* d_ws, size_t ws_size,
                              hipStream_t stream) {
  const float* emb = (const float*)d_in[0];
  const float* W0  = (const float*)d_in[1];
  const float* W1  = (const float*)d_in[2];
  const float* W2  = (const float*)d_in[3];
  float* out = (float*)d_out;
  _Float16* ws = (_Float16*)d_ws;   // needs 327680 f16 = 640 KB

  // Weight repack: one block per 32-k block (32 + 64 + 64 = 160 blocks).
  prep_w_all<<<160, 256, 0, stream>>>(W0, W1, W2, ws);

  // 16384 batches / 16 per block = 1024 blocks of 256 threads (4 waves x 4 b).
  cin_main<<<1024, 256, 0, stream>>>(emb, ws, out);
}

// Round 5
// 208.044 us; speedup vs baseline: 1.0089x; 1.0089x over previous
//
#include <hip/hip_runtime.h>

// CIN cross-network, fused MFMA implementation (f16 inputs, fp32 accum).
// Round 5: explicit depth-1 register prefetch of B fragments (+x0 scalars)
// to break the load-latency convoy that pinned MfmaUtil at ~56%.
//
// y[b,n,d] = relu( sum_{m,h} x0[b,m,d] * xk[b,h,d] * W[m,h,n] )
// out[b, 64*l + n] = sum_d y  (per layer l)
//
// Per-wave: 4 private batches; all LDS regions wave-private => NO barriers
// in cin_main.

typedef _Float16 half8 __attribute__((ext_vector_type(8)));
typedef _Float16 half2v __attribute__((ext_vector_type(2)));
typedef float f32x4 __attribute__((ext_vector_type(4)));

#define OUT_STRIDE 192
#define X0R 33            // x0 row stride (f16): 66B -> column reads hit 16
                          // distinct banks (floor((33r+m)/2)%32 injective in r)
#define X0B (16 * X0R)    // 528 f16 per batch
#define XKR 72            // xk row stride: 64 + 8 pad (16B-aligned, 2-way max)
#define XKB 1152          // xk batch stride

// ---------------------------------------------------------------------------
// Weight repack (round-4, verified). (m*H+h) == k, so W_flat is [k][n] and the
// source for one 32-k block (kb) is a CONTIGUOUS 8KB tile. Stage via LDS
// (row pad 65), emit fragment order:
//   dst[((kb*4 + t)*64 + lane)*8 + j] = W[k*64 + n],
//   k = kb*32 + (lane>>4)*8 + j,  n = t*16 + (lane&15)
__global__ void prep_w_all(const float* __restrict__ W0,
                           const float* __restrict__ W1,
                           const float* __restrict__ W2,
                           _Float16* __restrict__ dst) {
  __shared__ float tile[32 * 65];
  const int tid = threadIdx.x;
  const int blk = blockIdx.x;
  const float* src;
  _Float16* d;
  int kb;
  if (blk < 32)      { src = W0 + (size_t)blk * 2048;        d = dst;          kb = blk; }
  else if (blk < 96) { src = W1 + (size_t)(blk - 32) * 2048; d = dst + 65536;  kb = blk - 32; }
  else               { src = W2 + (size_t)(blk - 96) * 2048; d = dst + 196608; kb = blk - 96; }
#pragma unroll
  for (int i = tid; i < 2048; i += 256)
    tile[(i >> 6) * 65 + (i & 63)] = src[i];
  __syncthreads();
  const int lane = tid & 63, t = tid >> 6;
  const int qq = lane >> 4, n = t * 16 + (lane & 15);
  half8 v;
#pragma unroll
  for (int j = 0; j < 8; ++j)
    v[j] = (_Float16)tile[(qq * 8 + j) * 65 + n];
  *(half8*)(d + (size_t)kb * 2048 + tid * 8) = v;
}

// ---------------------------------------------------------------------------
// One layer for one wave's 4 private batches, software-pipelined depth 1.
// NHI: 32-wide h-blocks (1 for H=32, 2 for H=64). av[b][hi] in registers.
// x0row0 = x0 LDS base + r*X0R (lane-resolved); scalar reads conflict-free.
template<int NHI, bool LAST>
__device__ __forceinline__ void run_layer(
    const _Float16* __restrict__ Wp, const half8 (&av)[4][NHI],
    const _Float16* x0row0, _Float16* xkw, float* __restrict__ out,
    long gb0, int loff, int lane, int r, int q)
{
  const int NKB = 32 * NHI;
  const int NST = NKB / 2;

  f32x4 acc[4][4];
#pragma unroll
  for (int b = 0; b < 4; ++b)
#pragma unroll
    for (int t = 0; t < 4; ++t) acc[b][t] = (f32x4){0.f, 0.f, 0.f, 0.f};

  const _Float16* Wl = Wp + lane * 8;

#define MFMA_KB(BREG, XS, HI)                                      \
  {                                                                \
    _Pragma("unroll")                                              \
    for (int b = 0; b < 4; ++b) {                                  \
      half8 af;                                                    \
      half2v* ap = (half2v*)&af;                                   \
      const half2v* vp = (const half2v*)&av[b][HI];                \
      _Pragma("unroll")                                            \
      for (int j2 = 0; j2 < 4; ++j2) ap[j2] = vp[j2] * XS[b];      \
      _Pragma("unroll")                                            \
      for (int t = 0; t < 4; ++t)                                  \
        acc[b][t] = __builtin_amdgcn_mfma_f32_16x16x32_f16(        \
            af, BREG[t], acc[b][t], 0, 0, 0);                      \
    }                                                              \
  }

#define LOADXS(DST, MM)                                            \
  {                                                                \
    _Pragma("unroll")                                              \
    for (int b = 0; b < 4; ++b) {                                  \
      _Float16 x = x0row0[b * X0B + (MM)];                         \
      DST[b] = (half2v){x, x};                                     \
    }                                                              \
  }

  // Prologue: B for kb=0 and x0 scalar(s) for m=0 in flight before the loop.
  half8 Bc[4];
#pragma unroll
  for (int t = 0; t < 4; ++t) Bc[t] = *(const half8*)(Wl + t * 512);
  half2v xs0[4];
  LOADXS(xs0, 0);
  half2v xs1[4];                 // used only when NHI == 1 (m changes per kb)

  for (int s = 0; s < NST - 1; ++s) {
    const int kb0 = 2 * s;
    // -- phase A: prefetch kb0+1, then compute kb0 (hi=0, m=xs0) --
    half8 Bn[4];
    {
      const _Float16* p = Wl + (size_t)(kb0 + 1) * 2048;
#pragma unroll
      for (int t = 0; t < 4; ++t) Bn[t] = *(const half8*)(p + t * 512);
    }
    if constexpr (NHI == 1) LOADXS(xs1, kb0 + 1);
    MFMA_KB(Bc, xs0, 0);
    // -- phase B: prefetch kb0+2 (+next xs), then compute kb0+1 --
    half8 Bn2[4];
    {
      const _Float16* p = Wl + (size_t)(kb0 + 2) * 2048;
#pragma unroll
      for (int t = 0; t < 4; ++t) Bn2[t] = *(const half8*)(p + t * 512);
    }
    half2v xsn[4];
    if constexpr (NHI == 1) { LOADXS(xsn, kb0 + 2); }
    else                    { LOADXS(xsn, s + 1); }
    if constexpr (NHI == 1) { MFMA_KB(Bn, xs1, 0); }
    else                    { MFMA_KB(Bn, xs0, NHI - 1); }
    // rotate
#pragma unroll
    for (int t = 0; t < 4; ++t) Bc[t] = Bn2[t];
#pragma unroll
    for (int b = 0; b < 4; ++b) xs0[b] = xsn[b];
  }
  // -- final step (kb = NKB-2, NKB-1): no next-step prefetch --
  {
    const int kb0 = NKB - 2;
    half8 Bn[4];
    const _Float16* p = Wl + (size_t)(kb0 + 1) * 2048;
#pragma unroll
    for (int t = 0; t < 4; ++t) Bn[t] = *(const half8*)(p + t * 512);
    if constexpr (NHI == 1) LOADXS(xs1, kb0 + 1);
    MFMA_KB(Bc, xs0, 0);
    if constexpr (NHI == 1) { MFMA_KB(Bn, xs1, 0); }
    else                    { MFMA_KB(Bn, xs0, NHI - 1); }
  }
#undef MFMA_KB
#undef LOADXS

  // Epilogue (round-1 verified). C/D layout: col n = r, row d = q*4 + reg.
#pragma unroll
  for (int b = 0; b < 4; ++b) {
#pragma unroll
    for (int t = 0; t < 4; ++t) {
      float s = 0.f;
#pragma unroll
      for (int rr = 0; rr < 4; ++rr) {
        float v = acc[b][t][rr];
        v = v > 0.f ? v : 0.f;
        s += v;
        if (!LAST)
          xkw[b * XKB + (q * 4 + rr) * XKR + t * 16 + r] = (_Float16)v;
      }
      s += __shfl_xor(s, 16);
      s += __shfl_xor(s, 32);
      if (q == 0)
        out[(gb0 + b) * OUT_STRIDE + loff + t * 16 + r] = s;
    }
  }
}

__global__ __launch_bounds__(256, 3) void cin_main(
    const float* __restrict__ emb, const _Float16* __restrict__ Wall,
    float* __restrict__ out)
{
  // x0: 16 batches * 528 f16 (16 d rows of stride 33) = 16896 B
  // xk: 16 batches * 1152 f16 (16 d rows of stride 72) = 36864 B
  // total 53760 B -> 3 blocks/CU (161280 <= 163840).
  __shared__ __align__(16) _Float16 lds[16 * X0B + 16 * XKB];
  const int lane = threadIdx.x & 63;
  const int wv = threadIdx.x >> 6;
  const int r = lane & 15, q = lane >> 4;
  const long gb0 = (long)blockIdx.x * 16 + wv * 4;

  _Float16* x0w = &lds[wv * 4 * X0B];
  _Float16* xkw = &lds[16 * X0B + wv * 4 * XKB];

  // Stage this wave's 4 batches: read (m,d) fp32, write transposed (d,m) f16.
#pragma unroll
  for (int bb = 0; bb < 4; ++bb) {
    const float* src = emb + (gb0 + bb) * 512;
    _Float16* dstb = x0w + bb * X0B;
#pragma unroll
    for (int i = 0; i < 2; ++i) {
      int f = i * 256 + lane * 4;         // flat = m*16 + d, d aligned to 4
      float4 v = *(const float4*)(src + f);
      int m = f >> 4, d = f & 15;
      dstb[(d + 0) * X0R + m] = (_Float16)v.x;
      dstb[(d + 1) * X0R + m] = (_Float16)v.y;
      dstb[(d + 2) * X0R + m] = (_Float16)v.z;
      dstb[(d + 3) * X0R + m] = (_Float16)v.w;
    }
  }
  // All LDS regions are wave-private: program order + waitcnt suffice.

  const _Float16* x0row0 = x0w + r * X0R;

  // Layer 1: A-vectors av1[b][j] = x0[m=q*8+j, d=r] (8 scalar reads, one-time;
  // stride-33 rows are only 2B-aligned so no vector load here).
  half8 av1[4][1];
#pragma unroll
  for (int b = 0; b < 4; ++b)
#pragma unroll
    for (int j = 0; j < 8; ++j)
      av1[b][0][j] = x0row0[b * X0B + q * 8 + j];
  run_layer<1, false>(Wall, av1, x0row0, xkw, out, gb0, 0, lane, r, q);

  // Layer 2: A-vectors from xk (h = hi*32 + q*8 + j), 16B-aligned b128 loads.
  half8 av2[4][2];
#pragma unroll
  for (int b = 0; b < 4; ++b)
#pragma unroll
    for (int hi = 0; hi < 2; ++hi)
      av2[b][hi] = *(const half8*)(xkw + b * XKB + r * XKR + hi * 32 + q * 8);
  run_layer<2, false>(Wall + 65536, av2, x0row0, xkw, out, gb0, 64, lane, r, q);

  // Layer 3: reload A-vectors (layer 2 rewrote xk).
#pragma unroll
  for (int b = 0; b < 4; ++b)
#pragma unroll
    for (int hi = 0; hi < 2; ++hi)
      av2[b][hi] = *(const half8*)(xkw + b * XKB + r * XKR + hi * 32 + q * 8);
  run_layer<2, true>(Wall + 196608, av2, x0row0, xkw, out, gb0, 128, lane, r, q);
}

extern "C" void kernel_launch(void* const* d_in, const int* in_sizes, int n_in,
                              void* d_out, int out_size, void* d_ws, size_t ws_size,
                              hipStream_t stream) {
  const float* emb = (const float*)d_in[0];
  const float* W0  = (const float*)d_in[1];
  const float* W1  = (const float*)d_in[2];
  const float* W2  = (const float*)d_in[3];
  float* out = (float*)d_out;
  _Float16* ws = (_Float16*)d_ws;   // needs 327680 f16 = 640 KB

  // Weight repack: one block per 32-k block (32 + 64 + 64 = 160 blocks).
  prep_w_all<<<160, 256, 0, stream>>>(W0, W1, W2, ws);

  // 16384 batches / 16 per block = 1024 blocks of 256 threads (4 waves x 4 b).
  cin_main<<<1024, 256, 0, stream>>>(emb, ws, out);
}